// Round 17
// baseline (171.793 us; speedup 1.0000x reference)
//
#include <hip/hip_runtime.h>
#include <hip/hip_bf16.h>

// ---------------------------------------------------------------------------
// ConditionalHMM: B=8, T=512, D=768, S=8, H=32, O=32
// Outputs (flat): [ ll(1) | log_trans(B*T*H*H=4194304) | log_emiss(B*T*S*H*O=33554432) ]
// ---------------------------------------------------------------------------

typedef __attribute__((ext_vector_type(8))) short bf16x8;
typedef __attribute__((ext_vector_type(4))) float f32x4;

// ---- workspace byte offsets -----------------------------------------------
#define B_MBF   0            // M_trans linear bf16 [4096][1024]    8,388,608
#define B_LDOT  16777216     // per-s log-dots  [4096][8][32] f32   4,194,304
                             //   (region reused after k_elep by chunk scan:)
#define B_CHNK  16777216     //   chunk matrices [2][8][32][32][32] f32  2 MB
#define B_ABND  18874368     //   alpha boundaries [8][32][32] f32    32,768
#define B_BBND  18907136     //   beta  boundaries [8][32][32] f32    32,768
#define B_PART  18939904     //   ll partials [4096][3] f32            49,152
#define B_LEP   20971520     // lep [4096][32] f32                    524,288
#define B_ELEP  21496064     // elep [4096][32] f32                   524,288
#define B_ALIN  22020352     // alpha_lin [4096][32]                  524,288
#define B_BLIN  22544640     // beta_lin  [4096][32]                  524,288
#define B_TRSM  23068928     // softmax(unnorm_trans) [1024]            4,096
#define B_EMSM  23073024     // softmax(unnorm_emiss) [8192]           32,768
#define B_OBSM  23105792     // obs_mod [4096][8][32] f32           4,194,304
#define B_ABF   27447552     // emb bf16 [4096][768]                6,291,456
#define B_WTBF  33739008     // W^T bf16 [9216][768]               14,155,776

#define OUT_TR_BASE 1
#define OUT_EM_BASE 4194305

// ---- helpers ---------------------------------------------------------------
__device__ __forceinline__ float wsum32(float v) {
#pragma unroll
  for (int m = 16; m >= 1; m >>= 1) v += __shfl_xor(v, m);
  return v;
}
__device__ __forceinline__ float wmax32(float v) {
#pragma unroll
  for (int m = 16; m >= 1; m >>= 1) v = fmaxf(v, __shfl_xor(v, m));
  return v;
}
__device__ __forceinline__ short f2bf(float f) {
  union { float f; unsigned int u; } c; c.f = f;
  unsigned int u = c.u;
  unsigned int r = (u + 0x7FFFu + ((u >> 16) & 1u)) >> 16;  // RNE
  return (short)r;
}
__device__ __forceinline__ float bf2f(short h) {
  union { unsigned int u; float f; } c;
  c.u = ((unsigned int)(unsigned short)h) << 16;
  return c.f;
}
// async global->LDS, 16B per lane; LDS dest = wave-uniform base + lane*16
__device__ __forceinline__ void gload16(const void* g, void* l) {
  __builtin_amdgcn_global_load_lds(
      (const __attribute__((address_space(1))) unsigned int*)g,
      (__attribute__((address_space(3))) unsigned int*)l, 16, 0, 0);
}

// ---- fused prep kernel ------------------------------------------------------
// blk [0,3072):        emb -> bf16
// blk [3072,9984):     W^T bf16 build (288 n-tiles x 24 k-tiles)
// blk [9984,14080):    obs normalize
// blk [14080,14116):   softmax rows of unnorm_trans/emiss (8 rows/block)
__global__ __launch_bounds__(256) void k_prep(
    const float* __restrict__ emb, short* __restrict__ Abf,
    const float* __restrict__ Wt, const float* __restrict__ We,
    short* __restrict__ WT,
    const float* __restrict__ ut, const float* __restrict__ ue,
    float* __restrict__ tsm, float* __restrict__ esm,
    const float* __restrict__ obs, float* __restrict__ om) {
  __shared__ float tile[32][33];
  __shared__ int lbs_s[8];
  __shared__ int entf;
  const int blk = blockIdx.x;
  const int tid = threadIdx.x;
  if (blk < 3072) {                         // ---- emb -> bf16
    const int idx = (blk * 256 + tid) * 4;
#pragma unroll
    for (int c = 0; c < 4; ++c) Abf[idx + c] = f2bf(emb[idx + c]);
  } else if (blk < 9984) {                  // ---- W^T build
    const int x = blk - 3072;
    const int nb = (x % 288) * 32, kb = (x / 288) * 32;
    const int tx = tid & 31, ty = tid >> 5;
#pragma unroll
    for (int ii = 0; ii < 4; ++ii) {
      const int k = kb + ty + ii * 8;
      const int n = nb + tx;
      float v;
      if (n < 1024) v = Wt[(size_t)k * 1024 + n];
      else {
        const int ne = n - 1024, s = ne >> 10, c = ne & 1023;
        v = We[((size_t)s * 768 + k) * 1024 + c];
      }
      tile[ty + ii * 8][tx] = v;
    }
    __syncthreads();
#pragma unroll
    for (int ii = 0; ii < 4; ++ii) {
      const int n = nb + ty + ii * 8;
      const int k = kb + tx;
      WT[(size_t)n * 768 + k] = f2bf(tile[tx][ty + ii * 8]);
    }
  } else if (blk < 14080) {                 // ---- obs normalize
    const int bt = blk - 9984;
    const int o = tid & 31;
    const float v = obs[((size_t)bt << 8) + tid];
    float bv = v; int am = o;
#pragma unroll
    for (int m = 16; m >= 1; m >>= 1) {
      const float ov_ = __shfl_xor(bv, m);
      const int oa = __shfl_xor(am, m);
      if (ov_ > bv || (ov_ == bv && oa < am)) { bv = ov_; am = oa; }
    }
    if (o == 0) lbs_s[tid >> 5] = am;
    __syncthreads();
    if (tid == 0) {
      int e = 0;
#pragma unroll
      for (int s = 0; s < 8; ++s) e += lbs_s[s];
      entf = (e > 0) ? 1 : 0;
    }
    __syncthreads();
    const bool msk = entf && (lbs_s[tid >> 5] == 0);
    const float sub = (o == 0) ? 0.01f : (0.99f / 32.0f);
    om[((size_t)bt << 8) + tid] = msk ? sub : v;
  } else {                                  // ---- param softmax rows
    const int row = (blk - 14080) * 8 + (tid >> 5);
    const int j = tid & 31;
    const float* src; float* dst;
    if (row < 32) { src = ut + row * 32; dst = tsm + row * 32; }
    else          { src = ue + (row - 32) * 32; dst = esm + (row - 32) * 32; }
    float v = src[j];
    float mx = wmax32(v);
    float e = __expf(v - mx);
    float s = wsum32(e);
    dst[j] = e / s;
  }
}

// ---- fused GEMM: logits -> softmax -> mix -> log + lep dots ----------------
// 3-buffer BK=32 counted-vmcnt pipeline (T3/T4 minimum) with a CONFLICT-FREE
// pair-interleaved LDS layout: 64B rows are stored two-per-128B-line with
//   slot(r,c) = (r>>1)*8 + (((r&1)+2c) ^ ((r>>1)&7))      (16B slots)
// A wave's b128 read hits 64 distinct slots (2 lanes/bank = free). Staging
// keeps gload_lds's linear dest and inverse-permutes the per-lane GLOBAL
// source (rule #21). One raw barrier per tile; vmcnt(2) (FIFO) before it.
#define BM 128
#define BN 128
#define BK 32

__global__ __launch_bounds__(512, 4) void gemm_epi(
    const short* __restrict__ A, const short* __restrict__ WT,
    const float* __restrict__ btb, const float* __restrict__ beb,
    const float* __restrict__ tsm, const float* __restrict__ esm,
    const float* __restrict__ om,
    float* __restrict__ out, short* __restrict__ Mbf, float* __restrict__ ldot) {
  // 3 x (A 8KB @ +0, B 8KB @ +8192); om tile [128][36] f32 overlays in epilogue.
  __shared__ __align__(16) char smem[49152];
  float* lsOm = (float*)smem;            // overlay (epilogue only)

  // XCD swizzle: grid = 2304 = 8 XCD x (9 n-tiles x 32 m-tiles)
  const int bid = blockIdx.x;
  const int xcd = bid & 7;
  const int local = bid >> 3;            // 0..287
  const int ntile = xcd * 9 + (local % 9);
  const int mtile = local / 9;
  const int m0 = mtile * BM;
  const int n0 = ntile * BN;

  const int tid = threadIdx.x;
  const int lane = tid & 63;
  const int w = tid >> 6;                // 0..7
  const int wr = w >> 1, wc = w & 1;     // wr 0..3 (rows of 32), wc 0..1 (cols of 64)
  const int l15 = lane & 15, lq = lane >> 4;

  // staging: lane lam writes panel slot 64w+lam (linear LDS); global source is
  // the inverse permutation: jh=(lam&7)^(lam>>3); row=16w+2(lam>>3)+(jh&1); c=jh>>1.
  const int jh = (lane & 7) ^ (lane >> 3);
  const int srow = (w << 4) + ((lane >> 3) << 1) + (jh & 1);
  const int sc = jh >> 1;
  const short* gA = A + (size_t)(m0 + srow) * 768 + (sc << 3);
  const short* gB = WT + (size_t)(n0 + srow) * 768 + (sc << 3);
  const int lofs = (w << 10) + (lane << 4);

  // read byte-offsets (per-lane constants)
  int offA[2], offB[4];
#pragma unroll
  for (int mi = 0; mi < 2; ++mi) {
    const int r = wr * 32 + mi * 16 + l15;
    offA[mi] = ((r >> 1) << 7) + (((((r & 1)) + (lq << 1)) ^ ((r >> 1) & 7)) << 4);
  }
#pragma unroll
  for (int ni = 0; ni < 4; ++ni) {
    const int r = wc * 64 + ni * 16 + l15;
    offB[ni] = 8192 + (((r >> 1)) << 7) + ((((r & 1) + (lq << 1)) ^ ((r >> 1) & 7)) << 4);
  }

  f32x4 acc[2][4] = {};

  auto STAGE = [&](int bi, int kt) {
    char* d = smem + (bi << 14) + lofs;
    gload16(gA + kt, d);
    gload16(gB + kt, d + 8192);
  };

  STAGE(0, 0);
  STAGE(1, 32);
  asm volatile("s_waitcnt vmcnt(2)" ::: "memory");   // tile 0's pair landed
  __builtin_amdgcn_s_barrier();
  __builtin_amdgcn_sched_barrier(0);

  int b0 = 0, b1 = 1, b2 = 2;
#pragma unroll 3
  for (int it = 0; it < 24; ++it) {
    if (it < 22) STAGE(b2, (it + 2) * 32);
    const char* s = smem + (b0 << 14);
    bf16x8 af[2], bfr[4];
#pragma unroll
    for (int mi = 0; mi < 2; ++mi) af[mi] = *(const bf16x8*)(s + offA[mi]);
#pragma unroll
    for (int ni = 0; ni < 4; ++ni) bfr[ni] = *(const bf16x8*)(s + offB[ni]);
#pragma unroll
    for (int mi = 0; mi < 2; ++mi)
#pragma unroll
      for (int ni = 0; ni < 4; ++ni)
        acc[mi][ni] = __builtin_amdgcn_mfma_f32_16x16x32_bf16(af[mi], bfr[ni], acc[mi][ni], 0, 0, 0);
    // FIFO retirement: outstanding = pairs (it+1, it+2); vmcnt(2) => it+1 done.
    if (it < 22)      asm volatile("s_waitcnt vmcnt(2)" ::: "memory");
    else if (it < 23) asm volatile("s_waitcnt vmcnt(0)" ::: "memory");
    __builtin_amdgcn_sched_barrier(0);
    __builtin_amdgcn_s_barrier();        // readers of b0 done -> b0 reusable
    __builtin_amdgcn_sched_barrier(0);
    const int tb = b0; b0 = b1; b1 = b2; b2 = tb;
  }

  // ---- epilogue ------------------------------------------------------------
  const bool isem = (n0 >= 1024);        // block-uniform
  int sblk = 0;
  if (isem) {
    sblk = (n0 - 1024) >> 10;
    const int row = tid >> 2, part = (tid & 3) << 3;
    const float* src = om + (((size_t)(m0 + row)) << 8) + (sblk << 5) + part;
    float* dst = lsOm + row * 36 + part;
    *(float4*)dst = *(const float4*)src;
    *(float4*)(dst + 4) = *(const float4*)(src + 4);
    __syncthreads();
  }

  // No max-subtraction: |logits| < ~12 -> exp safe in f32.
#pragma unroll
  for (int g = 0; g < 2; ++g) {
    const int nbase = n0 + wc * 64 + g * 32;
    const int c0 = nbase + l15;
    const int c1 = c0 + 16;
    const float bias0 = isem ? beb[c0 - 1024] : btb[c0];
    const float bias1 = isem ? beb[c1 - 1024] : btb[c1];
    const float base0 = isem ? esm[c0 - 1024] : tsm[c0];
    const float base1 = isem ? esm[c1 - 1024] : tsm[c1];
    const int h = (nbase >> 5) & 31;
#pragma unroll
    for (int mi = 0; mi < 2; ++mi) {
      const int rl0 = wr * 32 + mi * 16 + lq * 4;
      const int rowb = m0 + rl0;
      float e0[4], e1[4], sm[4];
#pragma unroll
      for (int r = 0; r < 4; ++r) {
        e0[r] = __expf(acc[mi][2 * g][r] + bias0);
        e1[r] = __expf(acc[mi][2 * g + 1][r] + bias1);
        sm[r] = e0[r] + e1[r];
      }
#pragma unroll
      for (int m_ = 1; m_ < 16; m_ <<= 1) {
#pragma unroll
        for (int r = 0; r < 4; ++r) sm[r] += __shfl_xor(sm[r], m_);
      }
      float M0[4], M1[4], lg0[4], lg1[4];
#pragma unroll
      for (int r = 0; r < 4; ++r) {
        const float inv = 0.5f * __builtin_amdgcn_rcpf(sm[r]);
        M0[r] = 0.5f * base0 + e0[r] * inv;
        M1[r] = 0.5f * base1 + e1[r] * inv;
        lg0[r] = __logf(M0[r]);
        lg1[r] = __logf(M1[r]);
      }
      if (!isem) {
#pragma unroll
        for (int r = 0; r < 4; ++r) {
          const size_t rb = ((size_t)(rowb + r)) << 10;
          out[OUT_TR_BASE + rb + c0] = lg0[r];
          out[OUT_TR_BASE + rb + c1] = lg1[r];
          Mbf[rb + c0] = f2bf(M0[r]);
          Mbf[rb + c1] = f2bf(M1[r]);
        }
      } else {
        const int ne0 = c0 - 1024;
        float dt[4];
#pragma unroll
        for (int r = 0; r < 4; ++r) {
          const float* ov = lsOm + (rl0 + r) * 36;
          dt[r] = M0[r] * ov[l15] + M1[r] * ov[l15 + 16];
        }
#pragma unroll
        for (int m_ = 1; m_ < 16; m_ <<= 1) {
#pragma unroll
          for (int r = 0; r < 4; ++r) dt[r] += __shfl_xor(dt[r], m_);
        }
#pragma unroll
        for (int r = 0; r < 4; ++r) {
          const size_t rb = ((size_t)(rowb + r)) << 13;
          out[OUT_EM_BASE + rb + ne0] = lg0[r];
          out[OUT_EM_BASE + rb + ne0 + 16] = lg1[r];
        }
        if (l15 == 0) {
#pragma unroll
          for (int r = 0; r < 4; ++r)
            ldot[(((size_t)(rowb + r)) << 8) + (sblk << 5) + h] = __logf(dt[r]);
        }
      }
    }
  }
}

// lep = sum_s ldot ; elep = exp(lep - max_h lep)
__global__ __launch_bounds__(64) void k_elep(const float* __restrict__ ldot,
                                             float* __restrict__ lep,
                                             float* __restrict__ elep) {
  const int bt = blockIdx.x;
  const int l = threadIdx.x, i = l & 31;
  const float* ld = ldot + ((size_t)bt << 8);
  float v = 0.f;
#pragma unroll
  for (int s = 0; s < 8; ++s) v += ld[(s << 5) + i];
  float mx = wmax32(v);
  if (l < 32) {
    lep[((size_t)bt << 5) + i] = v;
    elep[((size_t)bt << 5) + i] = __expf(v - mx);
  }
}

// ---------------------------------------------------------------------------
// Blocked scan over bf16 M. G_t = M_t * diag(e_t).
// ---------------------------------------------------------------------------
__global__ __launch_bounds__(256) void k_chunk(const short* __restrict__ Mbf,
                                               const float* __restrict__ elep,
                                               float* __restrict__ chnk) {
  const int blk = blockIdx.x;          // dir*256 + b*32 + c
  const int dir = blk >> 8;
  const int b = (blk >> 5) & 7, c = blk & 31;
  int t0, t1;
  if (dir == 0) { t0 = 16 * c + 1; t1 = 16 * c + 16; if (t1 > 511) t1 = 511; }
  else          { t0 = 16 * c;     t1 = 16 * c + 15; if (t1 > 510) t1 = 510; }
  const size_t base = (size_t)b << 9;
  __shared__ float Pl[1024];
  __shared__ float Gl[1024];
  __shared__ float red[4];
  const int tid = threadIdx.x;
  const int r = tid >> 3;              // owns P[r][cq..cq+3]
  const int cq = (tid & 7) << 2;
  float4 p;
  {
    const short4 mh = *(const short4*)(Mbf + ((base + t0) << 10) + (tid << 2));
    const float4 e = *(const float4*)(elep + ((base + t0) << 5) + cq);
    p.x = bf2f(mh.x) * e.x; p.y = bf2f(mh.y) * e.y;
    p.z = bf2f(mh.z) * e.z; p.w = bf2f(mh.w) * e.w;
  }
  for (int t = t0 + 1; t <= t1; ++t) {
    *(float4*)(Pl + (tid << 2)) = p;
    const short4 mh = *(const short4*)(Mbf + ((base + t) << 10) + (tid << 2));
    const float4 e = *(const float4*)(elep + ((base + t) << 5) + cq);
    float4 g;
    g.x = bf2f(mh.x) * e.x; g.y = bf2f(mh.y) * e.y;
    g.z = bf2f(mh.z) * e.z; g.w = bf2f(mh.w) * e.w;
    *(float4*)(Gl + (tid << 2)) = g;
    __syncthreads();
    float4 nv = {0.f, 0.f, 0.f, 0.f};
#pragma unroll
    for (int j = 0; j < 32; ++j) {
      const float pr = Pl[(r << 5) + j];
      const float4 gj = *(const float4*)(Gl + (j << 5) + cq);
      nv.x = fmaf(pr, gj.x, nv.x);
      nv.y = fmaf(pr, gj.y, nv.y);
      nv.z = fmaf(pr, gj.z, nv.z);
      nv.w = fmaf(pr, gj.w, nv.w);
    }
    float mx = fmaxf(fmaxf(nv.x, nv.y), fmaxf(nv.z, nv.w));
#pragma unroll
    for (int mm = 32; mm >= 1; mm >>= 1) mx = fmaxf(mx, __shfl_xor(mx, mm));
    if ((tid & 63) == 0) red[tid >> 6] = mx;
    __syncthreads();
    mx = fmaxf(fmaxf(red[0], red[1]), fmaxf(red[2], red[3]));
    const float rs = __builtin_amdgcn_rcpf(mx);
    p.x = nv.x * rs; p.y = nv.y * rs; p.z = nv.z * rs; p.w = nv.w * rs;
  }
  *(float4*)(chnk + ((size_t)blk << 10) + (tid << 2)) = p;
}

__global__ __launch_bounds__(64) void k_stitch(const float* __restrict__ chnk,
                                               const float* __restrict__ elep,
                                               const float* __restrict__ sp,
                                               float* __restrict__ ab,
                                               float* __restrict__ bb) {
  const int l = threadIdx.x, i = l & 31, half = l >> 5;
  const int bid = blockIdx.x;
  const int b = bid & 7;
  float v;
  float pb0[16], pb1[16];
  if (bid < 8) {                       // forward: a across chunk boundaries
    const float* base = chnk + ((size_t)(b << 5) << 10);
    auto LDP = [&](float (&pb)[16], int c) {
      const float* P = base + ((size_t)c << 10) + ((half << 4) << 5) + i;
#pragma unroll
      for (int jj = 0; jj < 16; ++jj) pb[jj] = P[jj << 5];
    };
    auto STEP = [&](float (&pb)[16], int c) {   // v = norm(v * P_c)
      float pj[16];
#pragma unroll
      for (int jj = 0; jj < 16; ++jj) pj[jj] = __shfl(v, (half << 4) + jj);
      float a0 = 0.f, a1 = 0.f, a2 = 0.f, a3 = 0.f;
#pragma unroll
      for (int q = 0; q < 4; ++q) {
        a0 = fmaf(pj[(q << 2) + 0], pb[(q << 2) + 0], a0);
        a1 = fmaf(pj[(q << 2) + 1], pb[(q << 2) + 1], a1);
        a2 = fmaf(pj[(q << 2) + 2], pb[(q << 2) + 2], a2);
        a3 = fmaf(pj[(q << 2) + 3], pb[(q << 2) + 3], a3);
      }
      float av = (a0 + a1) + (a2 + a3);
      av += __shfl_xor(av, 32);
      const float S = wsum32(av);
      v = av * __builtin_amdgcn_rcpf(S);
      if (l < 32) ab[(((b << 5) + (c + 1)) << 5) + i] = v;
    };
    {  // a_0
      float u = sp[i];
      float mx = wmax32(u);
      float pe = __expf(u - mx);
      float s = wsum32(pe);
      v = (pe / s) * elep[((size_t)(b << 9) << 5) + i];
      float S = wsum32(v);
      v /= S;
      if (l < 32) ab[((b << 5) << 5) + i] = v;
    }
    LDP(pb0, 0);
    int c = 0;
    for (; c + 1 <= 30; c += 2) {
      LDP(pb1, c + 1);
      STEP(pb0, c);
      LDP(pb0, (c + 2 <= 30) ? c + 2 : 30);
      STEP(pb1, c + 1);
    }
    if (c == 30) STEP(pb0, 30);
  } else {                             // backward: b across chunk boundaries
    const float* base = chnk + ((size_t)(256 + (b << 5)) << 10);
    auto LDP = [&](float (&pb)[16], int c) {
      const float4* P = (const float4*)(base + ((size_t)c << 10) + (i << 5) + (half << 4));
#pragma unroll
      for (int q = 0; q < 4; ++q) {
        const float4 x = P[q];
        pb[(q << 2) + 0] = x.x; pb[(q << 2) + 1] = x.y;
        pb[(q << 2) + 2] = x.z; pb[(q << 2) + 3] = x.w;
      }
    };
    auto STEP = [&](float (&pb)[16], int c) {   // v = norm(P_c * v)
      float qj[16];
#pragma unroll
      for (int jj = 0; jj < 16; ++jj) qj[jj] = __shfl(v, (half << 4) + jj);
      float a0 = 0.f, a1 = 0.f, a2 = 0.f, a3 = 0.f;
#pragma unroll
      for (int q = 0; q < 4; ++q) {
        a0 = fmaf(qj[(q << 2) + 0], pb[(q << 2) + 0], a0);
        a1 = fmaf(qj[(q << 2) + 1], pb[(q << 2) + 1], a1);
        a2 = fmaf(qj[(q << 2) + 2], pb[(q << 2) + 2], a2);
        a3 = fmaf(qj[(q << 2) + 3], pb[(q << 2) + 3], a3);
      }
      float av = (a0 + a1) + (a2 + a3);
      av += __shfl_xor(av, 32);
      const float S = wsum32(av);
      v = av * __builtin_amdgcn_rcpf(S);
      if (l < 32) bb[(((b << 5) + c) << 5) + i] = v;
    };
    v = 1.0f / 32.0f;                  // b_511
    LDP(pb0, 31);
    int c = 31;
    for (; c - 1 >= 1; c -= 2) {
      LDP(pb1, c - 1);
      STEP(pb0, c);
      LDP(pb0, (c - 2 >= 1) ? c - 2 : 1);
      STEP(pb1, c - 1);
    }
    if (c == 1) STEP(pb0, 1);
  }
}

__global__ __launch_bounds__(64) void k_recon(const short* __restrict__ Mbf,
                                              const float* __restrict__ elep,
                                              const float* __restrict__ ab,
                                              const float* __restrict__ bb,
                                              float* __restrict__ alin,
                                              float* __restrict__ blin) {
  const int l = threadIdx.x, i = l & 31, half = l >> 5;
  const int blk = blockIdx.x;          // dir*256 + b*32 + c
  const int dir = blk >> 8;
  const int b = (blk >> 5) & 7, c = blk & 31;
  const size_t base = (size_t)b << 9;
  const short* Mb = Mbf + (base << 10);
  const float* Eb = elep + (base << 5);
  float v;
  float m0[16], m1[16];
  float e0, e1;
  if (dir == 0) {
    float* Ab = alin + (base << 5);
    const int cb = ((half << 4) << 5) + i;
    auto LDF = [&](float (&mb)[16], float& eb, int t) {
      const short* Mr = Mb + ((size_t)t << 10) + cb;
#pragma unroll
      for (int jj = 0; jj < 16; ++jj) mb[jj] = bf2f(Mr[jj << 5]);
      eb = Eb[(t << 5) + i];
    };
    auto STEPF = [&](float (&mb)[16], float eb, int t) {
      float pj[16];
#pragma unroll
      for (int jj = 0; jj < 16; ++jj) pj[jj] = __shfl(v, (half << 4) + jj);
      float a0 = 0.f, a1 = 0.f, a2 = 0.f, a3 = 0.f;
#pragma unroll
      for (int q = 0; q < 4; ++q) {
        a0 = fmaf(pj[(q << 2) + 0], mb[(q << 2) + 0], a0);
        a1 = fmaf(pj[(q << 2) + 1], mb[(q << 2) + 1], a1);
        a2 = fmaf(pj[(q << 2) + 2], mb[(q << 2) + 2], a2);
        a3 = fmaf(pj[(q << 2) + 3], mb[(q << 2) + 3], a3);
      }
      float av = (a0 + a1) + (a2 + a3);
      av += __shfl_xor(av, 32);
      const float nv = av * eb;
      const float S = wsum32(nv);
      v = nv * __builtin_amdgcn_rcpf(S);
      if (l < 32) Ab[(t << 5) + i] = v;
    };
    v = ab[(((b << 5) + c) << 5) + i];
    const int t0 = c << 4;
    if (l < 32) Ab[(t0 << 5) + i] = v;
    const int te = t0 + 15;
    LDF(m0, e0, t0 + 1);
    int t = t0 + 1;
    for (; t + 1 <= te; t += 2) {
      LDF(m1, e1, t + 1);
      STEPF(m0, e0, t);
      LDF(m0, e0, (t + 2 <= te) ? t + 2 : te);
      STEPF(m1, e1, t + 1);
    }
    if (t == te) STEPF(m0, e0, t);
  } else {
    float* Bb = blin + (base << 5);
    auto LDB = [&](float (&mb)[16], float& eb, int t) {
      const short4* Mr = (const short4*)(Mb + ((size_t)t << 10) + (i << 5) + (half << 4));
#pragma unroll
      for (int q = 0; q < 4; ++q) {
        const short4 x = Mr[q];
        mb[(q << 2) + 0] = bf2f(x.x); mb[(q << 2) + 1] = bf2f(x.y);
        mb[(q << 2) + 2] = bf2f(x.z); mb[(q << 2) + 3] = bf2f(x.w);
      }
      eb = Eb[(t << 5) + i];
    };
    auto STEPB = [&](float (&mb)[16], float eb, int t) {
      const float q0 = v * eb;
      float qj[16];
#pragma unroll
      for (int jj = 0; jj < 16; ++jj) qj[jj] = __shfl(q0, (half << 4) + jj);
      float a0 = 0.f, a1 = 0.f, a2 = 0.f, a3 = 0.f;
#pragma unroll
      for (int q = 0; q < 4; ++q) {
        a0 = fmaf(qj[(q << 2) + 0], mb[(q << 2) + 0], a0);
        a1 = fmaf(qj[(q << 2) + 1], mb[(q << 2) + 1], a1);
        a2 = fmaf(qj[(q << 2) + 2], mb[(q << 2) + 2], a2);
        a3 = fmaf(qj[(q << 2) + 3], mb[(q << 2) + 3], a3);
      }
      float av = (a0 + a1) + (a2 + a3);
      av += __shfl_xor(av, 32);
      const float S = wsum32(av);
      v = av * __builtin_amdgcn_rcpf(S);
      if (l < 32) Bb[(t << 5) + i] = v;
    };
    int ts;
    if (c == 31) {
      v = 1.0f / 32.0f;
      if (l < 32) Bb[(511 << 5) + i] = v;
      ts = 510;
    } else {
      v = bb[(((b << 5) + (c + 1)) << 5) + i];
      ts = (c << 4) + 15;
    }
    const int te = c << 4;
    LDB(m0, e0, ts);
    int t = ts;
    for (; t - 1 >= te; t -= 2) {
      LDB(m1, e1, t - 1);
      STEPB(m0, e0, t);
      LDB(m0, e0, (t - 2 >= te) ? t - 2 : te);
      STEPB(m1, e1, t - 1);
    }
    if (t == te) STEPB(m0, e0, t);
  }
}

// gamma / xi terms; one wave per (b,t). NO atomics: per-bt partials are
// written to part[bt][3] and reduced by k_ll.
__global__ __launch_bounds__(64) void k_final(
    const float* __restrict__ out_log,
    const float* __restrict__ alin, const float* __restrict__ blin,
    const float* __restrict__ elep, const float* __restrict__ lep,
    const int* __restrict__ seqlen, const float* __restrict__ sp,
    float* __restrict__ part) {
  const int bt = blockIdx.x;
  const int b = bt >> 9, t = bt & 511;
  const int l = threadIdx.x, i = l & 31;
  const int L = seqlen[b];
  const int tb = (t + 512 - L) & 511;
  const float a = alin[((size_t)bt << 5) + i];
  const float br = blin[((((size_t)b << 9) + tb) << 5) + i];
  const float g = a * br;
  float Z = wsum32(g);
  Z = fmaxf(Z, 1e-37f);
  const float ng = g / Z;
  const float es = wsum32(ng * lep[((size_t)bt << 5) + i]);
  float pr = 0.0f;
  if (t == 0) {
    const float v = sp[i];
    const float mx = wmax32(v);
    const float pe = __expf(v - mx);
    const float ss = wsum32(pe);
    const float lsp = v - mx - __logf(ss);
    pr = wsum32(ng * lsp);
  }
  float tran = 0.0f;
  if (t >= 1) {
    const float u = elep[((size_t)bt << 5) + i] * br;
    const int jb = (l & 1) << 4;
    float uj[16];
#pragma unroll
    for (int jj = 0; jj < 16; ++jj) uj[jj] = __shfl(u, jb + jj);
    const float ap = alin[(((size_t)bt - 1) << 5) + (l >> 1)];
    const float* Lr = out_log + OUT_TR_BASE + ((size_t)bt << 10) + ((l >> 1) << 5) + jb;
    float accZ = 0.0f, accT = 0.0f;
#pragma unroll
    for (int c = 0; c < 16; ++c) {
      const float lv = Lr[c];
      const float wv = __expf(lv) * ap * uj[c];
      accZ += wv;
      accT = fmaf(wv, lv, accT);
    }
#pragma unroll
    for (int m_ = 32; m_ >= 1; m_ >>= 1) {
      accZ += __shfl_xor(accZ, m_);
      accT += __shfl_xor(accT, m_);
    }
    tran = accT / accZ;
  }
  if (l == 0) {
    part[bt * 3 + 0] = (t == 0) ? pr : 0.0f;            // t=0 always < L
    part[bt * 3 + 1] = (t >= 1 && t < L) ? tran : 0.0f;
    part[bt * 3 + 2] = (t < L) ? es : 0.0f;
  }
}

// reduce part[4096][3] -> ll; one 32-lane group per batch b
__global__ __launch_bounds__(256) void k_ll(const float* __restrict__ part,
                                            float* __restrict__ out) {
  __shared__ float red[8];
  const int tid = threadIdx.x;
  const int b = tid >> 5, i = tid & 31;
  float s = 0.0f;
#pragma unroll
  for (int k = 0; k < 16; ++k) {
    const int bt = (b << 9) + (k << 5) + i;
    s += part[bt * 3 + 0] + part[bt * 3 + 1] + part[bt * 3 + 2];
  }
  s = wsum32(s);
  if (i == 0) red[b] = s;
  __syncthreads();
  if (tid == 0) {
    float v = 0.0f;
#pragma unroll
    for (int b2 = 0; b2 < 8; ++b2) v += red[b2];
    out[0] = v / 8.0f;
  }
}

// ---------------------------------------------------------------------------
extern "C" void kernel_launch(void* const* d_in, const int* in_sizes, int n_in,
                              void* d_out, int out_size, void* d_ws, size_t ws_size,
                              hipStream_t stream) {
  const float* emb    = (const float*)d_in[0];
  const float* obs    = (const float*)d_in[1];
  const int*   seqlen = (const int*)  d_in[2];
  const float* sp     = (const float*)d_in[3];
  const float* utr    = (const float*)d_in[4];
  const float* uem    = (const float*)d_in[5];
  const float* Wt     = (const float*)d_in[6];
  const float* btb    = (const float*)d_in[7];
  const float* We     = (const float*)d_in[8];
  const float* beb    = (const float*)d_in[9];
  float* out = (float*)d_out;
  char* ws = (char*)d_ws;

  short* Mbf  = (short*)(ws + B_MBF);
  float* ldot = (float*)(ws + B_LDOT);
  float* chnk = (float*)(ws + B_CHNK);
  float* abnd = (float*)(ws + B_ABND);
  float* bbnd = (float*)(ws + B_BBND);
  float* part = (float*)(ws + B_PART);
  float* lep  = (float*)(ws + B_LEP);
  float* elep = (float*)(ws + B_ELEP);
  float* alin = (float*)(ws + B_ALIN);
  float* blin = (float*)(ws + B_BLIN);
  float* tsm  = (float*)(ws + B_TRSM);
  float* esm  = (float*)(ws + B_EMSM);
  float* om   = (float*)(ws + B_OBSM);
  short* Abf  = (short*)(ws + B_ABF);
  short* WTbf = (short*)(ws + B_WTBF);

  k_prep<<<14116, 256, 0, stream>>>(emb, Abf, Wt, We, WTbf, utr, uem, tsm, esm,
                                    obs, om);
  gemm_epi<<<2304, 512, 0, stream>>>(Abf, WTbf, btb, beb, tsm, esm, om,
                                     out, Mbf, ldot);
  k_elep<<<4096, 64, 0, stream>>>(ldot, lep, elep);
  k_chunk<<<512, 256, 0, stream>>>(Mbf, elep, chnk);
  k_stitch<<<16, 64, 0, stream>>>(chnk, elep, sp, abnd, bbnd);
  k_recon<<<512, 64, 0, stream>>>(Mbf, elep, abnd, bbnd, alin, blin);
  k_final<<<4096, 64, 0, stream>>>(out, alin, blin, elep, lep, seqlen, sp, part);
  k_ll<<<1, 256, 0, stream>>>(part, out);
}

// Round 18
// 163.832 us; speedup vs baseline: 1.0486x; 1.0486x over previous
//
#include <hip/hip_runtime.h>
#include <hip/hip_bf16.h>

// ---------------------------------------------------------------------------
// ConditionalHMM: B=8, T=512, D=768, S=8, H=32, O=32
// Outputs (flat): [ ll(1) | log_trans(B*T*H*H=4194304) | log_emiss(B*T*S*H*O=33554432) ]
// ---------------------------------------------------------------------------

typedef __attribute__((ext_vector_type(8))) short bf16x8;
typedef __attribute__((ext_vector_type(4))) float f32x4;

// ---- workspace byte offsets -----------------------------------------------
#define B_MBF   0            // M_trans linear bf16 [4096][1024]    8,388,608
#define B_LDOT  16777216     // per-s log-dots  [4096][8][32] f32   4,194,304
                             //   (region reused after k_elep by chunk scan:)
#define B_CHNK  16777216     //   chunk matrices [2][8][32][32][32] f32  2 MB
#define B_ABND  18874368     //   alpha boundaries [8][32][32] f32    32,768
#define B_BBND  18907136     //   beta  boundaries [8][32][32] f32    32,768
#define B_PART  18939904     //   ll partials [4096][3] f32            49,152
#define B_LEP   20971520     // lep [4096][32] f32                    524,288
#define B_ELEP  21496064     // elep [4096][32] f32                   524,288
#define B_ALIN  22020352     // alpha_lin [4096][32]                  524,288
#define B_BLIN  22544640     // beta_lin  [4096][32]                  524,288
#define B_TRSM  23068928     // softmax(unnorm_trans) [1024]            4,096
#define B_EMSM  23073024     // softmax(unnorm_emiss) [8192]           32,768
#define B_OBSM  23105792     // obs_mod [4096][8][32] f32           4,194,304
#define B_ABF   27447552     // emb bf16 [4096][768]                6,291,456
#define B_WTBF  33739008     // W^T bf16 [9216][768]               14,155,776

#define OUT_TR_BASE 1
#define OUT_EM_BASE 4194305

// ---- helpers ---------------------------------------------------------------
__device__ __forceinline__ float wsum32(float v) {
#pragma unroll
  for (int m = 16; m >= 1; m >>= 1) v += __shfl_xor(v, m);
  return v;
}
__device__ __forceinline__ float wmax32(float v) {
#pragma unroll
  for (int m = 16; m >= 1; m >>= 1) v = fmaxf(v, __shfl_xor(v, m));
  return v;
}
__device__ __forceinline__ short f2bf(float f) {
  union { float f; unsigned int u; } c; c.f = f;
  unsigned int u = c.u;
  unsigned int r = (u + 0x7FFFu + ((u >> 16) & 1u)) >> 16;  // RNE
  return (short)r;
}
__device__ __forceinline__ float bf2f(short h) {
  union { unsigned int u; float f; } c;
  c.u = ((unsigned int)(unsigned short)h) << 16;
  return c.f;
}
// async global->LDS, 16B per lane; LDS dest = wave-uniform base + lane*16
__device__ __forceinline__ void gload16(const void* g, void* l) {
  __builtin_amdgcn_global_load_lds(
      (const __attribute__((address_space(1))) unsigned int*)g,
      (__attribute__((address_space(3))) unsigned int*)l, 16, 0, 0);
}

// ---- fused prep kernel ------------------------------------------------------
// blk [0,3072):        emb -> bf16
// blk [3072,9984):     W^T bf16 build (288 n-tiles x 24 k-tiles)
// blk [9984,14080):    obs normalize
// blk [14080,14116):   softmax rows of unnorm_trans/emiss (8 rows/block)
__global__ __launch_bounds__(256) void k_prep(
    const float* __restrict__ emb, short* __restrict__ Abf,
    const float* __restrict__ Wt, const float* __restrict__ We,
    short* __restrict__ WT,
    const float* __restrict__ ut, const float* __restrict__ ue,
    float* __restrict__ tsm, float* __restrict__ esm,
    const float* __restrict__ obs, float* __restrict__ om) {
  __shared__ float tile[32][33];
  __shared__ int lbs_s[8];
  __shared__ int entf;
  const int blk = blockIdx.x;
  const int tid = threadIdx.x;
  if (blk < 3072) {                         // ---- emb -> bf16
    const int idx = (blk * 256 + tid) * 4;
#pragma unroll
    for (int c = 0; c < 4; ++c) Abf[idx + c] = f2bf(emb[idx + c]);
  } else if (blk < 9984) {                  // ---- W^T build
    const int x = blk - 3072;
    const int nb = (x % 288) * 32, kb = (x / 288) * 32;
    const int tx = tid & 31, ty = tid >> 5;
#pragma unroll
    for (int ii = 0; ii < 4; ++ii) {
      const int k = kb + ty + ii * 8;
      const int n = nb + tx;
      float v;
      if (n < 1024) v = Wt[(size_t)k * 1024 + n];
      else {
        const int ne = n - 1024, s = ne >> 10, c = ne & 1023;
        v = We[((size_t)s * 768 + k) * 1024 + c];
      }
      tile[ty + ii * 8][tx] = v;
    }
    __syncthreads();
#pragma unroll
    for (int ii = 0; ii < 4; ++ii) {
      const int n = nb + ty + ii * 8;
      const int k = kb + tx;
      WT[(size_t)n * 768 + k] = f2bf(tile[tx][ty + ii * 8]);
    }
  } else if (blk < 14080) {                 // ---- obs normalize
    const int bt = blk - 9984;
    const int o = tid & 31;
    const float v = obs[((size_t)bt << 8) + tid];
    float bv = v; int am = o;
#pragma unroll
    for (int m = 16; m >= 1; m >>= 1) {
      const float ov_ = __shfl_xor(bv, m);
      const int oa = __shfl_xor(am, m);
      if (ov_ > bv || (ov_ == bv && oa < am)) { bv = ov_; am = oa; }
    }
    if (o == 0) lbs_s[tid >> 5] = am;
    __syncthreads();
    if (tid == 0) {
      int e = 0;
#pragma unroll
      for (int s = 0; s < 8; ++s) e += lbs_s[s];
      entf = (e > 0) ? 1 : 0;
    }
    __syncthreads();
    const bool msk = entf && (lbs_s[tid >> 5] == 0);
    const float sub = (o == 0) ? 0.01f : (0.99f / 32.0f);
    om[((size_t)bt << 8) + tid] = msk ? sub : v;
  } else {                                  // ---- param softmax rows
    const int row = (blk - 14080) * 8 + (tid >> 5);
    const int j = tid & 31;
    const float* src; float* dst;
    if (row < 32) { src = ut + row * 32; dst = tsm + row * 32; }
    else          { src = ue + (row - 32) * 32; dst = esm + (row - 32) * 32; }
    float v = src[j];
    float mx = wmax32(v);
    float e = __expf(v - mx);
    float s = wsum32(e);
    dst[j] = e / s;
  }
}

// ---- fused GEMM: logits -> softmax -> mix -> log + lep dots ----------------
// r13 datapath (512 thr / 8 waves, 128x128 tile, acc[2][4], 32 KB LDS,
// XCD-aware swizzle). M stored as bf16 (halves downstream scan traffic).
#define BM 128
#define BN 128
#define BK 64

__global__ __launch_bounds__(512, 4) void gemm_epi(
    const short* __restrict__ A, const short* __restrict__ WT,
    const float* __restrict__ btb, const float* __restrict__ beb,
    const float* __restrict__ tsm, const float* __restrict__ esm,
    const float* __restrict__ om,
    float* __restrict__ out, short* __restrict__ Mbf, float* __restrict__ ldot) {
  // 32 KB staging LDS; reused as om tile [128][36] f32 in the emission epilogue.
  __shared__ __align__(16) char smem[32768];
  short* lsA = (short*)smem;             // 16 KB
  short* lsB = (short*)(smem + 16384);   // 16 KB
  float* lsOm = (float*)smem;            // overlay (epilogue only)

  // XCD swizzle: grid = 2304 = 8 XCD x (9 n-tiles x 32 m-tiles)
  const int bid = blockIdx.x;
  const int xcd = bid & 7;
  const int local = bid >> 3;            // 0..287
  const int ntile = xcd * 9 + (local % 9);
  const int mtile = local / 9;
  const int m0 = mtile * BM;
  const int n0 = ntile * BN;

  const int tid = threadIdx.x;
  const int lane = tid & 63;
  const int w = tid >> 6;                // 0..7
  const int wr = w >> 1, wc = w & 1;     // wr 0..3 (rows of 32), wc 0..1 (cols of 64)
  const int l15 = lane & 15, lq = lane >> 4;

  // staging: linear LDS dest, inverse-swizzled global source chunk
  const int lr = lane >> 3;              // row&7 within 8-row group
  const int lc = (lane & 7) ^ lr;        // swizzled source chunk index
  const short* gA = A + (size_t)(m0 + (w << 3) + lr) * 768 + (lc << 3);
  const short* gB = WT + (size_t)(n0 + (w << 3) + lr) * 768 + (lc << 3);
  const int lofs = (w << 10) + (lane << 4);
  char* lA = (char*)lsA + lofs;
  char* lB = (char*)lsB + lofs;

  f32x4 acc[2][4] = {};

  for (int kt = 0; kt < 768; kt += BK) {
#pragma unroll
    for (int it = 0; it < 2; ++it) {     // rows it*64 + w*8 + lr
      gload16(gA + it * (64 * 768) + kt, lA + (it << 13));
      gload16(gB + it * (64 * 768) + kt, lB + (it << 13));
    }
    __syncthreads();
#pragma unroll
    for (int kk = 0; kk < 2; ++kk) {
      const int kbyte = kk * 64 + lq * 16;
      bf16x8 af[2], bfr[4];
#pragma unroll
      for (int mi = 0; mi < 2; ++mi) {
        const int m = wr * 32 + mi * 16 + l15;
        af[mi] = *(const bf16x8*)((const char*)lsA + ((m * 128 + kbyte) ^ ((m & 7) << 4)));
      }
#pragma unroll
      for (int ni = 0; ni < 4; ++ni) {
        const int n = wc * 64 + ni * 16 + l15;
        bfr[ni] = *(const bf16x8*)((const char*)lsB + ((n * 128 + kbyte) ^ ((n & 7) << 4)));
      }
#pragma unroll
      for (int mi = 0; mi < 2; ++mi)
#pragma unroll
        for (int ni = 0; ni < 4; ++ni)
          acc[mi][ni] = __builtin_amdgcn_mfma_f32_16x16x32_bf16(af[mi], bfr[ni], acc[mi][ni], 0, 0, 0);
    }
    __syncthreads();
  }

  // ---- epilogue ------------------------------------------------------------
  const bool isem = (n0 >= 1024);        // block-uniform
  int sblk = 0;
  if (isem) {
    sblk = (n0 - 1024) >> 10;
    const int row = tid >> 2, part = (tid & 3) << 3;
    const float* src = om + (((size_t)(m0 + row)) << 8) + (sblk << 5) + part;
    float* dst = lsOm + row * 36 + part;
    *(float4*)dst = *(const float4*)src;
    *(float4*)(dst + 4) = *(const float4*)(src + 4);
    __syncthreads();
  }

  // No max-subtraction: |logits| < ~12 -> exp safe in f32.
#pragma unroll
  for (int g = 0; g < 2; ++g) {
    const int nbase = n0 + wc * 64 + g * 32;
    const int c0 = nbase + l15;
    const int c1 = c0 + 16;
    const float bias0 = isem ? beb[c0 - 1024] : btb[c0];
    const float bias1 = isem ? beb[c1 - 1024] : btb[c1];
    const float base0 = isem ? esm[c0 - 1024] : tsm[c0];
    const float base1 = isem ? esm[c1 - 1024] : tsm[c1];
    const int h = (nbase >> 5) & 31;
#pragma unroll
    for (int mi = 0; mi < 2; ++mi) {
      const int rl0 = wr * 32 + mi * 16 + lq * 4;
      const int rowb = m0 + rl0;
      float e0[4], e1[4], sm[4];
#pragma unroll
      for (int r = 0; r < 4; ++r) {
        e0[r] = __expf(acc[mi][2 * g][r] + bias0);
        e1[r] = __expf(acc[mi][2 * g + 1][r] + bias1);
        sm[r] = e0[r] + e1[r];
      }
#pragma unroll
      for (int m_ = 1; m_ < 16; m_ <<= 1) {
#pragma unroll
        for (int r = 0; r < 4; ++r) sm[r] += __shfl_xor(sm[r], m_);
      }
      float M0[4], M1[4], lg0[4], lg1[4];
#pragma unroll
      for (int r = 0; r < 4; ++r) {
        const float inv = 0.5f * __builtin_amdgcn_rcpf(sm[r]);
        M0[r] = 0.5f * base0 + e0[r] * inv;
        M1[r] = 0.5f * base1 + e1[r] * inv;
        lg0[r] = __logf(M0[r]);
        lg1[r] = __logf(M1[r]);
      }
      if (!isem) {
#pragma unroll
        for (int r = 0; r < 4; ++r) {
          const size_t rb = ((size_t)(rowb + r)) << 10;
          out[OUT_TR_BASE + rb + c0] = lg0[r];
          out[OUT_TR_BASE + rb + c1] = lg1[r];
          Mbf[rb + c0] = f2bf(M0[r]);
          Mbf[rb + c1] = f2bf(M1[r]);
        }
      } else {
        const int ne0 = c0 - 1024;
        float dt[4];
#pragma unroll
        for (int r = 0; r < 4; ++r) {
          const float* ov = lsOm + (rl0 + r) * 36;
          dt[r] = M0[r] * ov[l15] + M1[r] * ov[l15 + 16];
        }
#pragma unroll
        for (int m_ = 1; m_ < 16; m_ <<= 1) {
#pragma unroll
          for (int r = 0; r < 4; ++r) dt[r] += __shfl_xor(dt[r], m_);
        }
#pragma unroll
        for (int r = 0; r < 4; ++r) {
          const size_t rb = ((size_t)(rowb + r)) << 13;
          out[OUT_EM_BASE + rb + ne0] = lg0[r];
          out[OUT_EM_BASE + rb + ne0 + 16] = lg1[r];
        }
        if (l15 == 0) {
#pragma unroll
          for (int r = 0; r < 4; ++r)
            ldot[(((size_t)(rowb + r)) << 8) + (sblk << 5) + h] = __logf(dt[r]);
        }
      }
    }
  }
}

// lep = sum_s ldot ; elep = exp(lep - max_h lep)
__global__ __launch_bounds__(64) void k_elep(const float* __restrict__ ldot,
                                             float* __restrict__ lep,
                                             float* __restrict__ elep) {
  const int bt = blockIdx.x;
  const int l = threadIdx.x, i = l & 31;
  const float* ld = ldot + ((size_t)bt << 8);
  float v = 0.f;
#pragma unroll
  for (int s = 0; s < 8; ++s) v += ld[(s << 5) + i];
  float mx = wmax32(v);
  if (l < 32) {
    lep[((size_t)bt << 5) + i] = v;
    elep[((size_t)bt << 5) + i] = __expf(v - mx);
  }
}

// ---------------------------------------------------------------------------
// Blocked scan over bf16 M. G_t = M_t * diag(e_t).
// ---------------------------------------------------------------------------
__global__ __launch_bounds__(256) void k_chunk(const short* __restrict__ Mbf,
                                               const float* __restrict__ elep,
                                               float* __restrict__ chnk) {
  const int blk = blockIdx.x;          // dir*256 + b*32 + c
  const int dir = blk >> 8;
  const int b = (blk >> 5) & 7, c = blk & 31;
  int t0, t1;
  if (dir == 0) { t0 = 16 * c + 1; t1 = 16 * c + 16; if (t1 > 511) t1 = 511; }
  else          { t0 = 16 * c;     t1 = 16 * c + 15; if (t1 > 510) t1 = 510; }
  const size_t base = (size_t)b << 9;
  __shared__ float Pl[1024];
  __shared__ float Gl[1024];
  __shared__ float red[4];
  const int tid = threadIdx.x;
  const int r = tid >> 3;              // owns P[r][cq..cq+3]
  const int cq = (tid & 7) << 2;
  float4 p;
  {
    const short4 mh = *(const short4*)(Mbf + ((base + t0) << 10) + (tid << 2));
    const float4 e = *(const float4*)(elep + ((base + t0) << 5) + cq);
    p.x = bf2f(mh.x) * e.x; p.y = bf2f(mh.y) * e.y;
    p.z = bf2f(mh.z) * e.z; p.w = bf2f(mh.w) * e.w;
  }
  for (int t = t0 + 1; t <= t1; ++t) {
    *(float4*)(Pl + (tid << 2)) = p;
    const short4 mh = *(const short4*)(Mbf + ((base + t) << 10) + (tid << 2));
    const float4 e = *(const float4*)(elep + ((base + t) << 5) + cq);
    float4 g;
    g.x = bf2f(mh.x) * e.x; g.y = bf2f(mh.y) * e.y;
    g.z = bf2f(mh.z) * e.z; g.w = bf2f(mh.w) * e.w;
    *(float4*)(Gl + (tid << 2)) = g;
    __syncthreads();
    float4 nv = {0.f, 0.f, 0.f, 0.f};
#pragma unroll
    for (int j = 0; j < 32; ++j) {
      const float pr = Pl[(r << 5) + j];
      const float4 gj = *(const float4*)(Gl + (j << 5) + cq);
      nv.x = fmaf(pr, gj.x, nv.x);
      nv.y = fmaf(pr, gj.y, nv.y);
      nv.z = fmaf(pr, gj.z, nv.z);
      nv.w = fmaf(pr, gj.w, nv.w);
    }
    float mx = fmaxf(fmaxf(nv.x, nv.y), fmaxf(nv.z, nv.w));
#pragma unroll
    for (int mm = 32; mm >= 1; mm >>= 1) mx = fmaxf(mx, __shfl_xor(mx, mm));
    if ((tid & 63) == 0) red[tid >> 6] = mx;
    __syncthreads();
    mx = fmaxf(fmaxf(red[0], red[1]), fmaxf(red[2], red[3]));
    const float rs = __builtin_amdgcn_rcpf(mx);
    p.x = nv.x * rs; p.y = nv.y * rs; p.z = nv.z * rs; p.w = nv.w * rs;
  }
  *(float4*)(chnk + ((size_t)blk << 10) + (tid << 2)) = p;
}

__global__ __launch_bounds__(64) void k_stitch(const float* __restrict__ chnk,
                                               const float* __restrict__ elep,
                                               const float* __restrict__ sp,
                                               float* __restrict__ ab,
                                               float* __restrict__ bb) {
  const int l = threadIdx.x, i = l & 31, half = l >> 5;
  const int bid = blockIdx.x;
  const int b = bid & 7;
  float v;
  float pb0[16], pb1[16];
  if (bid < 8) {                       // forward: a across chunk boundaries
    const float* base = chnk + ((size_t)(b << 5) << 10);
    auto LDP = [&](float (&pb)[16], int c) {
      const float* P = base + ((size_t)c << 10) + ((half << 4) << 5) + i;
#pragma unroll
      for (int jj = 0; jj < 16; ++jj) pb[jj] = P[jj << 5];
    };
    auto STEP = [&](float (&pb)[16], int c) {   // v = norm(v * P_c)
      float pj[16];
#pragma unroll
      for (int jj = 0; jj < 16; ++jj) pj[jj] = __shfl(v, (half << 4) + jj);
      float a0 = 0.f, a1 = 0.f, a2 = 0.f, a3 = 0.f;
#pragma unroll
      for (int q = 0; q < 4; ++q) {
        a0 = fmaf(pj[(q << 2) + 0], pb[(q << 2) + 0], a0);
        a1 = fmaf(pj[(q << 2) + 1], pb[(q << 2) + 1], a1);
        a2 = fmaf(pj[(q << 2) + 2], pb[(q << 2) + 2], a2);
        a3 = fmaf(pj[(q << 2) + 3], pb[(q << 2) + 3], a3);
      }
      float av = (a0 + a1) + (a2 + a3);
      av += __shfl_xor(av, 32);
      const float S = wsum32(av);
      v = av * __builtin_amdgcn_rcpf(S);
      if (l < 32) ab[(((b << 5) + (c + 1)) << 5) + i] = v;
    };
    {  // a_0
      float u = sp[i];
      float mx = wmax32(u);
      float pe = __expf(u - mx);
      float s = wsum32(pe);
      v = (pe / s) * elep[((size_t)(b << 9) << 5) + i];
      float S = wsum32(v);
      v /= S;
      if (l < 32) ab[((b << 5) << 5) + i] = v;
    }
    LDP(pb0, 0);
    int c = 0;
    for (; c + 1 <= 30; c += 2) {
      LDP(pb1, c + 1);
      STEP(pb0, c);
      LDP(pb0, (c + 2 <= 30) ? c + 2 : 30);
      STEP(pb1, c + 1);
    }
    if (c == 30) STEP(pb0, 30);
  } else {                             // backward: b across chunk boundaries
    const float* base = chnk + ((size_t)(256 + (b << 5)) << 10);
    auto LDP = [&](float (&pb)[16], int c) {
      const float4* P = (const float4*)(base + ((size_t)c << 10) + (i << 5) + (half << 4));
#pragma unroll
      for (int q = 0; q < 4; ++q) {
        const float4 x = P[q];
        pb[(q << 2) + 0] = x.x; pb[(q << 2) + 1] = x.y;
        pb[(q << 2) + 2] = x.z; pb[(q << 2) + 3] = x.w;
      }
    };
    auto STEP = [&](float (&pb)[16], int c) {   // v = norm(P_c * v)
      float qj[16];
#pragma unroll
      for (int jj = 0; jj < 16; ++jj) qj[jj] = __shfl(v, (half << 4) + jj);
      float a0 = 0.f, a1 = 0.f, a2 = 0.f, a3 = 0.f;
#pragma unroll
      for (int q = 0; q < 4; ++q) {
        a0 = fmaf(qj[(q << 2) + 0], pb[(q << 2) + 0], a0);
        a1 = fmaf(qj[(q << 2) + 1], pb[(q << 2) + 1], a1);
        a2 = fmaf(qj[(q << 2) + 2], pb[(q << 2) + 2], a2);
        a3 = fmaf(qj[(q << 2) + 3], pb[(q << 2) + 3], a3);
      }
      float av = (a0 + a1) + (a2 + a3);
      av += __shfl_xor(av, 32);
      const float S = wsum32(av);
      v = av * __builtin_amdgcn_rcpf(S);
      if (l < 32) bb[(((b << 5) + c) << 5) + i] = v;
    };
    v = 1.0f / 32.0f;                  // b_511
    LDP(pb0, 31);
    int c = 31;
    for (; c - 1 >= 1; c -= 2) {
      LDP(pb1, c - 1);
      STEP(pb0, c);
      LDP(pb0, (c - 2 >= 1) ? c - 2 : 1);
      STEP(pb1, c - 1);
    }
    if (c == 1) STEP(pb0, 1);
  }
}

__global__ __launch_bounds__(64) void k_recon(const short* __restrict__ Mbf,
                                              const float* __restrict__ elep,
                                              const float* __restrict__ ab,
                                              const float* __restrict__ bb,
                                              float* __restrict__ alin,
                                              float* __restrict__ blin) {
  const int l = threadIdx.x, i = l & 31, half = l >> 5;
  const int blk = blockIdx.x;          // dir*256 + b*32 + c
  const int dir = blk >> 8;
  const int b = (blk >> 5) & 7, c = blk & 31;
  const size_t base = (size_t)b << 9;
  const short* Mb = Mbf + (base << 10);
  const float* Eb = elep + (base << 5);
  float v;
  float m0[16], m1[16];
  float e0, e1;
  if (dir == 0) {
    float* Ab = alin + (base << 5);
    const int cb = ((half << 4) << 5) + i;
    auto LDF = [&](float (&mb)[16], float& eb, int t) {
      const short* Mr = Mb + ((size_t)t << 10) + cb;
#pragma unroll
      for (int jj = 0; jj < 16; ++jj) mb[jj] = bf2f(Mr[jj << 5]);
      eb = Eb[(t << 5) + i];
    };
    auto STEPF = [&](float (&mb)[16], float eb, int t) {
      float pj[16];
#pragma unroll
      for (int jj = 0; jj < 16; ++jj) pj[jj] = __shfl(v, (half << 4) + jj);
      float a0 = 0.f, a1 = 0.f, a2 = 0.f, a3 = 0.f;
#pragma unroll
      for (int q = 0; q < 4; ++q) {
        a0 = fmaf(pj[(q << 2) + 0], mb[(q << 2) + 0], a0);
        a1 = fmaf(pj[(q << 2) + 1], mb[(q << 2) + 1], a1);
        a2 = fmaf(pj[(q << 2) + 2], mb[(q << 2) + 2], a2);
        a3 = fmaf(pj[(q << 2) + 3], mb[(q << 2) + 3], a3);
      }
      float av = (a0 + a1) + (a2 + a3);
      av += __shfl_xor(av, 32);
      const float nv = av * eb;
      const float S = wsum32(nv);
      v = nv * __builtin_amdgcn_rcpf(S);
      if (l < 32) Ab[(t << 5) + i] = v;
    };
    v = ab[(((b << 5) + c) << 5) + i];
    const int t0 = c << 4;
    if (l < 32) Ab[(t0 << 5) + i] = v;
    const int te = t0 + 15;
    LDF(m0, e0, t0 + 1);
    int t = t0 + 1;
    for (; t + 1 <= te; t += 2) {
      LDF(m1, e1, t + 1);
      STEPF(m0, e0, t);
      LDF(m0, e0, (t + 2 <= te) ? t + 2 : te);
      STEPF(m1, e1, t + 1);
    }
    if (t == te) STEPF(m0, e0, t);
  } else {
    float* Bb = blin + (base << 5);
    auto LDB = [&](float (&mb)[16], float& eb, int t) {
      const short4* Mr = (const short4*)(Mb + ((size_t)t << 10) + (i << 5) + (half << 4));
#pragma unroll
      for (int q = 0; q < 4; ++q) {
        const short4 x = Mr[q];
        mb[(q << 2) + 0] = bf2f(x.x); mb[(q << 2) + 1] = bf2f(x.y);
        mb[(q << 2) + 2] = bf2f(x.z); mb[(q << 2) + 3] = bf2f(x.w);
      }
      eb = Eb[(t << 5) + i];
    };
    auto STEPB = [&](float (&mb)[16], float eb, int t) {
      const float q0 = v * eb;
      float qj[16];
#pragma unroll
      for (int jj = 0; jj < 16; ++jj) qj[jj] = __shfl(q0, (half << 4) + jj);
      float a0 = 0.f, a1 = 0.f, a2 = 0.f, a3 = 0.f;
#pragma unroll
      for (int q = 0; q < 4; ++q) {
        a0 = fmaf(qj[(q << 2) + 0], mb[(q << 2) + 0], a0);
        a1 = fmaf(qj[(q << 2) + 1], mb[(q << 2) + 1], a1);
        a2 = fmaf(qj[(q << 2) + 2], mb[(q << 2) + 2], a2);
        a3 = fmaf(qj[(q << 2) + 3], mb[(q << 2) + 3], a3);
      }
      float av = (a0 + a1) + (a2 + a3);
      av += __shfl_xor(av, 32);
      const float S = wsum32(av);
      v = av * __builtin_amdgcn_rcpf(S);
      if (l < 32) Bb[(t << 5) + i] = v;
    };
    int ts;
    if (c == 31) {
      v = 1.0f / 32.0f;
      if (l < 32) Bb[(511 << 5) + i] = v;
      ts = 510;
    } else {
      v = bb[(((b << 5) + (c + 1)) << 5) + i];
      ts = (c << 4) + 15;
    }
    const int te = c << 4;
    LDB(m0, e0, ts);
    int t = ts;
    for (; t - 1 >= te; t -= 2) {
      LDB(m1, e1, t - 1);
      STEPB(m0, e0, t);
      LDB(m0, e0, (t - 2 >= te) ? t - 2 : te);
      STEPB(m1, e1, t - 1);
    }
    if (t == te) STEPB(m0, e0, t);
  }
}

// gamma / xi terms; one wave per (b,t). NO atomics: per-bt partials are
// written to part[bt][3] and reduced by k_ll.
__global__ __launch_bounds__(64) void k_final(
    const float* __restrict__ out_log,
    const float* __restrict__ alin, const float* __restrict__ blin,
    const float* __restrict__ elep, const float* __restrict__ lep,
    const int* __restrict__ seqlen, const float* __restrict__ sp,
    float* __restrict__ part) {
  const int bt = blockIdx.x;
  const int b = bt >> 9, t = bt & 511;
  const int l = threadIdx.x, i = l & 31;
  const int L = seqlen[b];
  const int tb = (t + 512 - L) & 511;
  const float a = alin[((size_t)bt << 5) + i];
  const float br = blin[((((size_t)b << 9) + tb) << 5) + i];
  const float g = a * br;
  float Z = wsum32(g);
  Z = fmaxf(Z, 1e-37f);
  const float ng = g / Z;
  const float es = wsum32(ng * lep[((size_t)bt << 5) + i]);
  float pr = 0.0f;
  if (t == 0) {
    const float v = sp[i];
    const float mx = wmax32(v);
    const float pe = __expf(v - mx);
    const float ss = wsum32(pe);
    const float lsp = v - mx - __logf(ss);
    pr = wsum32(ng * lsp);
  }
  float tran = 0.0f;
  if (t >= 1) {
    const float u = elep[((size_t)bt << 5) + i] * br;
    const int jb = (l & 1) << 4;
    float uj[16];
#pragma unroll
    for (int jj = 0; jj < 16; ++jj) uj[jj] = __shfl(u, jb + jj);
    const float ap = alin[(((size_t)bt - 1) << 5) + (l >> 1)];
    const float* Lr = out_log + OUT_TR_BASE + ((size_t)bt << 10) + ((l >> 1) << 5) + jb;
    float accZ = 0.0f, accT = 0.0f;
#pragma unroll
    for (int c = 0; c < 16; ++c) {
      const float lv = Lr[c];
      const float wv = __expf(lv) * ap * uj[c];
      accZ += wv;
      accT = fmaf(wv, lv, accT);
    }
#pragma unroll
    for (int m_ = 32; m_ >= 1; m_ >>= 1) {
      accZ += __shfl_xor(accZ, m_);
      accT += __shfl_xor(accT, m_);
    }
    tran = accT / accZ;
  }
  if (l == 0) {
    part[bt * 3 + 0] = (t == 0) ? pr : 0.0f;            // t=0 always < L
    part[bt * 3 + 1] = (t >= 1 && t < L) ? tran : 0.0f;
    part[bt * 3 + 2] = (t < L) ? es : 0.0f;
  }
}

// reduce part[4096][3] -> ll; one 32-lane group per batch b
__global__ __launch_bounds__(256) void k_ll(const float* __restrict__ part,
                                            float* __restrict__ out) {
  __shared__ float red[8];
  const int tid = threadIdx.x;
  const int b = tid >> 5, i = tid & 31;
  float s = 0.0f;
#pragma unroll
  for (int k = 0; k < 16; ++k) {
    const int bt = (b << 9) + (k << 5) + i;
    s += part[bt * 3 + 0] + part[bt * 3 + 1] + part[bt * 3 + 2];
  }
  s = wsum32(s);
  if (i == 0) red[b] = s;
  __syncthreads();
  if (tid == 0) {
    float v = 0.0f;
#pragma unroll
    for (int b2 = 0; b2 < 8; ++b2) v += red[b2];
    out[0] = v / 8.0f;
  }
}

// ---------------------------------------------------------------------------
extern "C" void kernel_launch(void* const* d_in, const int* in_sizes, int n_in,
                              void* d_out, int out_size, void* d_ws, size_t ws_size,
                              hipStream_t stream) {
  const float* emb    = (const float*)d_in[0];
  const float* obs    = (const float*)d_in[1];
  const int*   seqlen = (const int*)  d_in[2];
  const float* sp     = (const float*)d_in[3];
  const float* utr    = (const float*)d_in[4];
  const float* uem    = (const float*)d_in[5];
  const float* Wt     = (const float*)d_in[6];
  const float* btb    = (const float*)d_in[7];
  const float* We     = (const float*)d_in[8];
  const float* beb    = (const float*)d_in[9];
  float* out = (float*)d_out;
  char* ws = (char*)d_ws;

  short* Mbf  = (short*)(ws + B_MBF);
  float* ldot = (float*)(ws + B_LDOT);
  float* chnk = (float*)(ws + B_CHNK);
  float* abnd = (float*)(ws + B_ABND);
  float* bbnd = (float*)(ws + B_BBND);
  float* part = (float*)(ws + B_PART);
  float* lep  = (float*)(ws + B_LEP);
  float* elep = (float*)(ws + B_ELEP);
  float* alin = (float*)(ws + B_ALIN);
  float* blin = (float*)(ws + B_BLIN);
  float* tsm  = (float*)(ws + B_TRSM);
  float* esm  = (float*)(ws + B_EMSM);
  float* om   = (float*)(ws + B_OBSM);
  short* Abf  = (short*)(ws + B_ABF);
  short* WTbf = (short*)(ws + B_WTBF);

  k_prep<<<14116, 256, 0, stream>>>(emb, Abf, Wt, We, WTbf, utr, uem, tsm, esm,
                                    obs, om);
  gemm_epi<<<2304, 512, 0, stream>>>(Abf, WTbf, btb, beb, tsm, esm, om,
                                     out, Mbf, ldot);
  k_elep<<<4096, 64, 0, stream>>>(ldot, lep, elep);
  k_chunk<<<512, 256, 0, stream>>>(Mbf, elep, chnk);
  k_stitch<<<16, 64, 0, stream>>>(chnk, elep, sp, abnd, bbnd);
  k_recon<<<512, 64, 0, stream>>>(Mbf, elep, abnd, bbnd, alin, blin);
  k_final<<<4096, 64, 0, stream>>>(out, alin, blin, elep, lep, seqlen, sp, part);
  k_ll<<<1, 256, 0, stream>>>(part, out);
}